// Round 2
// baseline (155.258 us; speedup 1.0000x reference)
//
#include <hip/hip_runtime.h>

#define C_GMS 0.0026f

// DPP wavefront shifts: full-rate VALU cross-lane, zero LDS latency.
// dppL = value of lane-1 (wf_shr:1, 0x138), lane 0 reads 0 (bound_ctrl)
// dppR = value of lane+1 (wf_shl:1, 0x130), lane 63 reads 0
__device__ __forceinline__ float dppL(float x) {
    return __int_as_float(__builtin_amdgcn_mov_dpp(__float_as_int(x), 0x138, 0xf, 0xf, true));
}
__device__ __forceinline__ float dppR(float x) {
    return __int_as_float(__builtin_amdgcn_mov_dpp(__float_as_int(x), 0x130, 0xf, 0xf, true));
}
__device__ __forceinline__ float med3f(float a, float b, float c) {
    return __builtin_amdgcn_fmed3f(a, b, c);   // exact median-of-3, 1 instr
}

// partial layout: [0,9216) scale0 | [,14336) s1 | [,15104) s2 | [,15360) s3
// RC=8 for scale0 (64 chunks) and RC=4 for s1 (64 chunks): latency-bound
// regime (R1 post-mortem: VALUBusy 26%, occ 37%) -> buy TLP with waves.
#define N0 9216
#define N1 5120
#define N2 768
#define N3 256
#define NTOT 15360

// Rolling GMS core: one wave = 64-col strip, rolls down output rows.
// median9 = med3(max3(lo), med3(me), min3(hi)).
// gmap fused: 1-gmap = (a+b-2*sqrt(ab))/(a+b+9c), raw v_sqrt/v_rcp.
// Prefetch depth 2 (load->use = one full iteration), unroll 2.
template<class LoadFn, class PoolFn>
__device__ __forceinline__ float gms_core(int lane, int Hk, int R0, int iend, int c,
                                          int phalf, LoadFn loadrow2, PoolFn dopool)
{
    auto medrow = [&](float ga, float gb, float gc, float& m, float& rs) {
        float lo = fminf(fminf(ga, gb), gc);
        float me = med3f(ga, gb, gc);
        float hi = fmaxf(fmaxf(ga, gb), gc);
        float lmax = fmaxf(fmaxf(dppL(lo), lo), dppR(lo));
        float mid  = med3f(dppL(me), me, dppR(me));
        float hmin = fminf(fminf(dppL(hi), hi), dppR(hi));
        m  = med3f(lmax, mid, hmin);
        rs = m + dppL(m) + dppR(m);
    };

    float xa, ya, xb, yb, xc, yc, xd, yd, xe, ye;
    loadrow2(R0 - 1, xa, ya);
    loadrow2(R0,     xb, yb);
    loadrow2(R0 + 1, xc, yc);
    loadrow2(R0 + 2, xd, yd);
    loadrow2(R0 + 3, xe, ye);

    // depth-2 prefetch pipeline: n0 = row i+4 (consumed this iter),
    // n1 = row i+5 (consumed next iter)
    float n0x, n0y, n1x, n1y;
    loadrow2(R0 + 4, n0x, n0y);
    loadrow2(R0 + 5, n1x, n1y);

    float mx0, mx1, mx2, rx0, rx1, rx2;
    float my0, my1, my2, ry0, ry1, ry2;
    medrow(xa, xb, xc, mx0, rx0); medrow(ya, yb, yc, my0, ry0);
    dopool(xb, xc, yb, yc, phalf);             // pool gray rows (R0, R0+1)
    medrow(xb, xc, xd, mx1, rx1); medrow(yb, yc, yd, my1, ry1);
    medrow(xc, xd, xe, mx2, rx2); medrow(yc, yd, ye, my2, ry2);

    float gx2 = xd, gx3 = xe, gy2 = yd, gy3 = ye;  // gray rows i+2, i+3
    const bool outLane = (lane >= 2) && (lane <= 61) && (c <= Hk - 2);
    const float C9 = 9.0f * C_GMS;
    float acc = 0.0f;

    #pragma unroll 2
    for (int i = R0; i < iend; ++i) {
        // prefetch row i+6; uniform guard: never fetch past iend+3 (no
        // wasted HBM traffic at chunk tails)
        float pfx, pfy;
        {
            int rp = (i + 6 <= iend + 3) ? (i + 6) : -1;
            loadrow2(rp, pfx, pfy);
        }

        float csx = mx0 + mx1 + mx2;
        float csy = my0 + my1 + my2;
        float Gxx = dppR(csx) - dppL(csx);
        float Gxy = dppR(csy) - dppL(csy);
        float Gyx = rx0 - rx2;
        float Gyy = ry0 - ry2;
        // gI = sqrt(a)/3, gR = sqrt(b)/3  =>
        // 1 - gmap = (a + b - 2*sqrt(a*b)) / (a + b + 9c)
        float a = fmaf(Gxx, Gxx, Gyx * Gyx);
        float b = fmaf(Gxy, Gxy, Gyy * Gyy);
        float t = a + b;
        float s = __builtin_amdgcn_sqrtf(a * b);
        float den = t + C9;
        float diff = fmaf(-2.0f, s, t);
        float r = __builtin_amdgcn_rcpf(den);
        if (outLane) acc = fmaf(diff, r, acc);

        if (((i + 3) & 1) == 1) dopool(gx2, gx3, gy2, gy3, (i + 2) >> 1);

        float mxn, rxn, myn, ryn;
        medrow(gx2, gx3, n0x, mxn, rxn);
        medrow(gy2, gy3, n0y, myn, ryn);
        mx0 = mx1; mx1 = mx2; mx2 = mxn; rx0 = rx1; rx1 = rx2; rx2 = rxn;
        my0 = my1; my1 = my2; my2 = myn; ry0 = ry1; ry1 = ry2; ry2 = ryn;
        gx2 = gx3; gx3 = n0x; gy2 = gy3; gy3 = n0y;
        n0x = n1x; n0y = n1y; n1x = pfx; n1y = pfy;
    }

    for (int off = 32; off; off >>= 1) acc += __shfl_down(acc, off, 64);
    return acc;
}

// Dispatch A: scale0 from RGB + fused 2x2 pool -> X1/Y1. RC=8: 9216 waves
// = 36/CU (latency-bound regime needs TLP; RC=16 left CUs half-empty).
__global__ __launch_bounds__(256) void msgms_scale0(
    const float* __restrict__ Ii, const float* __restrict__ Ir,
    float* __restrict__ X1, float* __restrict__ Y1, float* __restrict__ P)
{
    const int lane = threadIdx.x & 63;
    const int u = blockIdx.x * 4 + (threadIdx.x >> 6);
    const int s  = u % 9;               // strip fastest: halo sharing in L2
    const int t1 = u / 9;
    const int k  = t1 % 64;             // 64 chunks of 8 rows
    const int b  = t1 / 64;

    const int c  = 60 * s - 1 + lane;
    const int R0 = k * 8;
    const int iend = min(R0 + 8, 510);

    const float* PX = Ii + (size_t)b * 3 * 262144;
    const float* PY = Ir + (size_t)b * 3 * 262144;
    const bool cok = (c >= 0) && (c < 512);

    auto loadrow2 = [&](int r, float& vx, float& vy) {
        vx = 0.0f; vy = 0.0f;
        if (r >= 0 && r < 512 && cok) {
            int o = r * 512 + c;
            vx = (PX[o] + PX[o + 262144] + PX[o + 524288]) * (1.0f / 3.0f);
            vy = (PY[o] + PY[o + 262144] + PY[o + 524288]) * (1.0f / 3.0f);
        }
    };

    const int phalf = R0 >> 1;
    const int pend  = min(phalf + 4, 256);   // 8 gray rows -> 4 pooled rows
    const bool poolLane = ((lane & 1) == 1) && (lane <= 59) && (c + 1 < 512);
    auto dopool = [&](float bx, float cx, float by, float cy, int p) {
        if (p < phalf || p >= pend) return;   // uniform
        float ux = bx + cx, uy = by + cy;
        float hx = ux + dppR(ux);
        float hy = uy + dppR(uy);
        if (poolLane) {
            size_t o = ((size_t)b * 256 + p) * 256 + (c >> 1);
            X1[o] = hx * 0.25f;
            Y1[o] = hy * 0.25f;
        }
    };

    float acc = gms_core(lane, 512, R0, iend, c, phalf, loadrow2, dopool);
    if (lane == 0) P[u] = acc;
}

// Dispatch B: scales 1-3 from X1/Y1 with GxG on-the-fly pooling (G=1,2,4).
// Plain stores; dispatch boundary provides coherence. ZERO fences/atomics.
template<int G, int RC>
__device__ __forceinline__ void phaseR(
    int u, const float* __restrict__ X1, const float* __restrict__ Y1,
    int nstrips, int nchunks, float* __restrict__ P)
{
    constexpr int Hk = 256 / G;
    const int lane = threadIdx.x & 63;
    const int s  = u % nstrips;
    const int t1 = u / nstrips;
    const int k  = t1 % nchunks;
    const int b  = t1 / nchunks;

    const int c  = 60 * s - 1 + lane;
    const int R0 = k * RC;
    const int iend = min(R0 + RC, Hk - 2);

    const float* Xp = X1 + (size_t)b * 65536;
    const float* Yp = Y1 + (size_t)b * 65536;
    const bool cok = (c >= 0) && (c < Hk);

    auto loadrow2 = [&](int r, float& vx, float& vy) {
        vx = 0.0f; vy = 0.0f;
        if (r >= 0 && r < Hk && cok) {
            if constexpr (G == 1) {
                int o = r * 256 + c;
                vx = Xp[o]; vy = Yp[o];
            } else if constexpr (G == 2) {
                int o = (r * 2) * 256 + c * 2;
                float2 a0 = *(const float2*)(Xp + o);
                float2 a1 = *(const float2*)(Xp + o + 256);
                float2 b0 = *(const float2*)(Yp + o);
                float2 b1 = *(const float2*)(Yp + o + 256);
                vx = ((a0.x + a0.y) + (a1.x + a1.y)) * 0.25f;
                vy = ((b0.x + b0.y) + (b1.x + b1.y)) * 0.25f;
            } else {
                int o = (r * 4) * 256 + c * 4;
                float sx = 0.0f, sy = 0.0f;
                #pragma unroll
                for (int fr = 0; fr < 4; ++fr) {
                    float4 t = *(const float4*)(Xp + o + fr * 256);
                    float4 q = *(const float4*)(Yp + o + fr * 256);
                    sx += (t.x + t.y) + (t.z + t.w);
                    sy += (q.x + q.y) + (q.z + q.w);
                }
                vx = sx * 0.0625f; vy = sy * 0.0625f;
            }
        }
    };
    auto nopool = [&](float, float, float, float, int) {};

    float acc = gms_core(lane, Hk, R0, iend, c, 0, loadrow2, nopool);
    if (lane == 0) P[u] = acc;
}

__global__ __launch_bounds__(256) void msgms_rest(
    const float* __restrict__ X1, const float* __restrict__ Y1,
    float* __restrict__ P)
{
    const int u = blockIdx.x * 4 + (threadIdx.x >> 6);
    if      (u < N1)      phaseR<1, 4>(u,           X1, Y1, 5, 64, P + N0);
    else if (u < N1 + N2) phaseR<2, 8>(u - N1,      X1, Y1, 3, 16, P + N0 + N1);
    else                  phaseR<4, 8>(u - N1 - N2, X1, Y1, 2,  8, P + N0 + N1 + N2);
}

// Dispatch C: one block, weighted sum of all partials. Plain loads.
__global__ __launch_bounds__(256) void msgms_final(
    const float* __restrict__ P, float* __restrict__ out)
{
    const int tid = threadIdx.x;
    const double w0 = 1.0 / (4.0 * 16.0 * 510.0 * 510.0);
    const double w1 = 1.0 / (4.0 * 16.0 * 254.0 * 254.0);
    const double w2 = 1.0 / (4.0 * 16.0 * 126.0 * 126.0);
    const double w3 = 1.0 / (4.0 * 16.0 * 62.0 * 62.0);
    double v = 0.0;
    for (int i = tid; i < NTOT; i += 256) {
        double w = (i < N0) ? w0 : (i < N0 + N1) ? w1 : (i < N0 + N1 + N2) ? w2 : w3;
        v += (double)P[i] * w;
    }
    for (int off = 32; off; off >>= 1) v += __shfl_down(v, off, 64);
    __shared__ double wsum[4];
    if ((tid & 63) == 0) wsum[tid >> 6] = v;
    __syncthreads();
    if (tid == 0) out[0] = (float)(wsum[0] + wsum[1] + wsum[2] + wsum[3]);
}

extern "C" void kernel_launch(void* const* d_in, const int* in_sizes, int n_in,
                              void* d_out, int out_size, void* d_ws, size_t ws_size,
                              hipStream_t stream) {
    const float* Ii = (const float*)d_in[0];
    const float* Ir = (const float*)d_in[1];
    float* out = (float*)d_out;

    char* ws = (char*)d_ws;
    float* P  = (float*)ws;                              // NTOT partials
    float* X1 = P + NTOT;                                // 16 x 256 x 256 gray
    float* Y1 = X1 + 16 * 256 * 256;

    msgms_scale0<<<N0 / 4, 256, 0, stream>>>(Ii, Ir, X1, Y1, P);
    msgms_rest<<<(N1 + N2 + N3) / 4, 256, 0, stream>>>(X1, Y1, P);
    msgms_final<<<1, 256, 0, stream>>>(P, out);
}

// Round 4
// 143.585 us; speedup vs baseline: 1.0813x; 1.0813x over previous
//
#include <hip/hip_runtime.h>

#define C_GMS 0.0026f

// DPP wavefront shifts: full-rate VALU cross-lane, zero LDS latency.
// dppL = value of lane-1 (wf_shr:1, 0x138), lane 0 reads 0 (bound_ctrl)
// dppR = value of lane+1 (wf_shl:1, 0x130), lane 63 reads 0
__device__ __forceinline__ float dppL(float x) {
    return __int_as_float(__builtin_amdgcn_mov_dpp(__float_as_int(x), 0x138, 0xf, 0xf, true));
}
__device__ __forceinline__ float dppR(float x) {
    return __int_as_float(__builtin_amdgcn_mov_dpp(__float_as_int(x), 0x130, 0xf, 0xf, true));
}
__device__ __forceinline__ float med3f(float a, float b, float c) {
    return __builtin_amdgcn_fmed3f(a, b, c);   // exact median-of-3, 1 instr
}

// partial layout: [0,4608) scale0 | [,7168) s1 | [,7936) s2 | [,8192) s3
// Geometry reverted to R1 (best measured): scale0 RC=16, rest RC=8.
// R2 lesson: more waves at more warmup overhead is a net loss.
#define N0 4608
#define N1 2560
#define N2 768
#define N3 256
#define NTOT 8192

// Rolling GMS core: one wave = 64-col strip, rolls down output rows.
// median9 = med3(max3(lo), med3(me), min3(hi)).
// gmap fused: 1-gmap = (a+b-2*sqrt(ab))/(a+b+9c), raw v_sqrt/v_rcp.
// Prefetch depth 2 (load->use = one full iteration), unroll 2.
// This revision: loadrow2 is BRANCHLESS (clamped addresses + one mask
// multiplier) so all 6 loads + prefetch stay in flight together — R2
// post-mortem implied ~1 outstanding load/wave (exec-guarded clusters).
template<class LoadFn, class PoolFn>
__device__ __forceinline__ float gms_core(int lane, int Hk, int R0, int iend, int c,
                                          int phalf, LoadFn loadrow2, PoolFn dopool)
{
    auto medrow = [&](float ga, float gb, float gc, float& m, float& rs) {
        float lo = fminf(fminf(ga, gb), gc);
        float me = med3f(ga, gb, gc);
        float hi = fmaxf(fmaxf(ga, gb), gc);
        float lmax = fmaxf(fmaxf(dppL(lo), lo), dppR(lo));
        float mid  = med3f(dppL(me), me, dppR(me));
        float hmin = fminf(fminf(dppL(hi), hi), dppR(hi));
        m  = med3f(lmax, mid, hmin);
        rs = m + dppL(m) + dppR(m);
    };

    float xa, ya, xb, yb, xc, yc, xd, yd, xe, ye;
    loadrow2(R0 - 1, xa, ya);
    loadrow2(R0,     xb, yb);
    loadrow2(R0 + 1, xc, yc);
    loadrow2(R0 + 2, xd, yd);
    loadrow2(R0 + 3, xe, ye);

    // depth-2 prefetch pipeline: n0 = row i+4 (consumed this iter),
    // n1 = row i+5 (consumed next iter)
    float n0x, n0y, n1x, n1y;
    loadrow2(R0 + 4, n0x, n0y);
    loadrow2(R0 + 5, n1x, n1y);

    float mx0, mx1, mx2, rx0, rx1, rx2;
    float my0, my1, my2, ry0, ry1, ry2;
    medrow(xa, xb, xc, mx0, rx0); medrow(ya, yb, yc, my0, ry0);
    dopool(xb, xc, yb, yc, phalf);             // pool gray rows (R0, R0+1)
    medrow(xb, xc, xd, mx1, rx1); medrow(yb, yc, yd, my1, ry1);
    medrow(xc, xd, xe, mx2, rx2); medrow(yc, yd, ye, my2, ry2);

    float gx2 = xd, gx3 = xe, gy2 = yd, gy3 = ye;  // gray rows i+2, i+3
    const bool outLane = (lane >= 2) && (lane <= 61) && (c <= Hk - 2);
    const float C9 = 9.0f * C_GMS;
    float acc = 0.0f;

    #pragma unroll 2
    for (int i = R0; i < iend; ++i) {
        // prefetch row i+6; tail guard keeps rp in a harmless (clamped,
        // masked-to-zero) range without fetching rows past iend+3
        float pfx, pfy;
        {
            int rp = (i + 6 <= iend + 3) ? (i + 6) : -1;
            loadrow2(rp, pfx, pfy);
        }

        float csx = mx0 + mx1 + mx2;
        float csy = my0 + my1 + my2;
        float Gxx = dppR(csx) - dppL(csx);
        float Gxy = dppR(csy) - dppL(csy);
        float Gyx = rx0 - rx2;
        float Gyy = ry0 - ry2;
        // gI = sqrt(a)/3, gR = sqrt(b)/3  =>
        // 1 - gmap = (a + b - 2*sqrt(a*b)) / (a + b + 9c)
        float a = fmaf(Gxx, Gxx, Gyx * Gyx);
        float b = fmaf(Gxy, Gxy, Gyy * Gyy);
        float t = a + b;
        float s = __builtin_amdgcn_sqrtf(a * b);
        float den = t + C9;
        float diff = fmaf(-2.0f, s, t);
        float r = __builtin_amdgcn_rcpf(den);
        if (outLane) acc = fmaf(diff, r, acc);

        if (((i + 3) & 1) == 1) dopool(gx2, gx3, gy2, gy3, (i + 2) >> 1);

        float mxn, rxn, myn, ryn;
        medrow(gx2, gx3, n0x, mxn, rxn);
        medrow(gy2, gy3, n0y, myn, ryn);
        mx0 = mx1; mx1 = mx2; mx2 = mxn; rx0 = rx1; rx1 = rx2; rx2 = rxn;
        my0 = my1; my1 = my2; my2 = myn; ry0 = ry1; ry1 = ry2; ry2 = ryn;
        gx2 = gx3; gx3 = n0x; gy2 = gy3; gy3 = n0y;
        n0x = n1x; n0y = n1y; n1x = pfx; n1y = pfy;
    }

    for (int off = 32; off; off >>= 1) acc += __shfl_down(acc, off, 64);
    return acc;
}

// Dispatch A: scale0 from RGB + fused 2x2 pool -> X1/Y1. RC=16.
__global__ __launch_bounds__(256) void msgms_scale0(
    const float* __restrict__ Ii, const float* __restrict__ Ir,
    float* __restrict__ X1, float* __restrict__ Y1, float* __restrict__ P)
{
    const int lane = threadIdx.x & 63;
    const int u = blockIdx.x * 4 + (threadIdx.x >> 6);
    const int s  = u % 9;               // strip fastest: halo sharing in L2
    const int t1 = u / 9;
    const int k  = t1 % 32;             // 32 chunks of 16 rows
    const int b  = t1 / 32;

    const int c  = 60 * s - 1 + lane;
    const int R0 = k * 16;
    const int iend = min(R0 + 16, 510);

    const float* PX = Ii + (size_t)b * 3 * 262144;
    const float* PY = Ir + (size_t)b * 3 * 262144;

    // branchless load setup: clamp col once, fold pad-zero + 1/3 into cw
    const int cc = min(max(c, 0), 511);
    const float cw = ((c >= 0) && (c < 512)) ? (1.0f / 3.0f) : 0.0f;

    auto loadrow2 = [&](int r, float& vx, float& vy) {
        int rc = min(max(r, 0), 511);          // uniform (SALU)
        float m = (r == rc) ? cw : 0.0f;       // row-valid fold
        int o = rc * 512 + cc;
        float x0 = PX[o], x1 = PX[o + 262144], x2 = PX[o + 524288];
        float y0 = PY[o], y1 = PY[o + 262144], y2 = PY[o + 524288];
        vx = (x0 + x1 + x2) * m;
        vy = (y0 + y1 + y2) * m;
    };

    const int phalf = R0 >> 1;
    const int pend  = min(phalf + 8, 256);   // 16 gray rows -> 8 pooled rows
    const bool poolLane = ((lane & 1) == 1) && (lane <= 59) && (c + 1 < 512);
    auto dopool = [&](float bx, float cx, float by, float cy, int p) {
        if (p < phalf || p >= pend) return;   // uniform
        float ux = bx + cx, uy = by + cy;
        float hx = ux + dppR(ux);
        float hy = uy + dppR(uy);
        if (poolLane) {
            size_t o = ((size_t)b * 256 + p) * 256 + (c >> 1);
            X1[o] = hx * 0.25f;
            Y1[o] = hy * 0.25f;
        }
    };

    float acc = gms_core(lane, 512, R0, iend, c, phalf, loadrow2, dopool);
    if (lane == 0) P[u] = acc;
}

// Dispatch B: scales 1-3 from X1/Y1 with GxG on-the-fly pooling (G=1,2,4).
// Plain stores; dispatch boundary provides coherence. ZERO fences/atomics.
template<int G>
__device__ __forceinline__ void phaseR(
    int u, const float* __restrict__ X1, const float* __restrict__ Y1,
    int nstrips, int nchunks, float* __restrict__ P)
{
    constexpr int Hk = 256 / G;
    const int lane = threadIdx.x & 63;
    const int s  = u % nstrips;
    const int t1 = u / nstrips;
    const int k  = t1 % nchunks;
    const int b  = t1 / nchunks;

    const int c  = 60 * s - 1 + lane;
    const int R0 = k * 8;
    const int iend = min(R0 + 8, Hk - 2);

    const float* Xp = X1 + (size_t)b * 65536;
    const float* Yp = Y1 + (size_t)b * 65536;

    // branchless load setup: clamped col + mask folded into pool scale
    const int cc = min(max(c, 0), Hk - 1);
    const float cval = ((c >= 0) && (c < Hk)) ? 1.0f : 0.0f;

    auto loadrow2 = [&](int r, float& vx, float& vy) {
        int rc = min(max(r, 0), Hk - 1);       // uniform (SALU)
        float m = (r == rc) ? cval : 0.0f;
        if constexpr (G == 1) {
            int o = rc * 256 + cc;
            vx = Xp[o] * m; vy = Yp[o] * m;
        } else if constexpr (G == 2) {
            int o = (rc * 2) * 256 + cc * 2;
            float2 a0 = *(const float2*)(Xp + o);
            float2 a1 = *(const float2*)(Xp + o + 256);
            float2 b0 = *(const float2*)(Yp + o);
            float2 b1 = *(const float2*)(Yp + o + 256);
            float q = 0.25f * m;
            vx = ((a0.x + a0.y) + (a1.x + a1.y)) * q;
            vy = ((b0.x + b0.y) + (b1.x + b1.y)) * q;
        } else {
            int o = (rc * 4) * 256 + cc * 4;
            float sx = 0.0f, sy = 0.0f;
            #pragma unroll
            for (int fr = 0; fr < 4; ++fr) {
                float4 t = *(const float4*)(Xp + o + fr * 256);
                float4 q = *(const float4*)(Yp + o + fr * 256);
                sx += (t.x + t.y) + (t.z + t.w);
                sy += (q.x + q.y) + (q.z + q.w);
            }
            float q = 0.0625f * m;
            vx = sx * q; vy = sy * q;
        }
    };
    auto nopool = [&](float, float, float, float, int) {};

    float acc = gms_core(lane, Hk, R0, iend, c, 0, loadrow2, nopool);
    if (lane == 0) P[u] = acc;
}

__global__ __launch_bounds__(256) void msgms_rest(
    const float* __restrict__ X1, const float* __restrict__ Y1,
    float* __restrict__ P)
{
    const int u = blockIdx.x * 4 + (threadIdx.x >> 6);
    if      (u < N1)      phaseR<1>(u,           X1, Y1, 5, 32, P + N0);
    else if (u < N1 + N2) phaseR<2>(u - N1,      X1, Y1, 3, 16, P + N0 + N1);
    else                  phaseR<4>(u - N1 - N2, X1, Y1, 2,  8, P + N0 + N1 + N2);
}

// Dispatch C: one block, weighted sum of all partials. Plain loads.
__global__ __launch_bounds__(256) void msgms_final(
    const float* __restrict__ P, float* __restrict__ out)
{
    const int tid = threadIdx.x;
    const double w0 = 1.0 / (4.0 * 16.0 * 510.0 * 510.0);
    const double w1 = 1.0 / (4.0 * 16.0 * 254.0 * 254.0);
    const double w2 = 1.0 / (4.0 * 16.0 * 126.0 * 126.0);
    const double w3 = 1.0 / (4.0 * 16.0 * 62.0 * 62.0);
    double v = 0.0;
    for (int i = tid; i < NTOT; i += 256) {
        double w = (i < N0) ? w0 : (i < N0 + N1) ? w1 : (i < N0 + N1 + N2) ? w2 : w3;
        v += (double)P[i] * w;
    }
    for (int off = 32; off; off >>= 1) v += __shfl_down(v, off, 64);
    __shared__ double wsum[4];
    if ((tid & 63) == 0) wsum[tid >> 6] = v;
    __syncthreads();
    if (tid == 0) out[0] = (float)(wsum[0] + wsum[1] + wsum[2] + wsum[3]);
}

extern "C" void kernel_launch(void* const* d_in, const int* in_sizes, int n_in,
                              void* d_out, int out_size, void* d_ws, size_t ws_size,
                              hipStream_t stream) {
    const float* Ii = (const float*)d_in[0];
    const float* Ir = (const float*)d_in[1];
    float* out = (float*)d_out;

    char* ws = (char*)d_ws;
    float* P  = (float*)ws;                              // NTOT partials
    float* X1 = P + NTOT;                                // 16 x 256 x 256 gray
    float* Y1 = X1 + 16 * 256 * 256;

    msgms_scale0<<<N0 / 4, 256, 0, stream>>>(Ii, Ir, X1, Y1, P);
    msgms_rest<<<(N1 + N2 + N3) / 4, 256, 0, stream>>>(X1, Y1, P);
    msgms_final<<<1, 256, 0, stream>>>(P, out);
}

// Round 5
// 140.394 us; speedup vs baseline: 1.1059x; 1.0227x over previous
//
#include <hip/hip_runtime.h>

#define C_GMS 0.0026f

// DPP wavefront shifts: full-rate VALU cross-lane, zero LDS latency.
// dppL = value of lane-1 (wf_shr:1, 0x138), lane 0 reads 0 (bound_ctrl)
// dppR = value of lane+1 (wf_shl:1, 0x130), lane 63 reads 0
__device__ __forceinline__ float dppL(float x) {
    return __int_as_float(__builtin_amdgcn_mov_dpp(__float_as_int(x), 0x138, 0xf, 0xf, true));
}
__device__ __forceinline__ float dppR(float x) {
    return __int_as_float(__builtin_amdgcn_mov_dpp(__float_as_int(x), 0x130, 0xf, 0xf, true));
}
__device__ __forceinline__ float med3f(float a, float b, float c) {
    return __builtin_amdgcn_fmed3f(a, b, c);   // exact median-of-3, 1 instr
}

// partial layout: [0,4608) scale0 | [,7168) s1 | [,7936) s2 | [,8192) s3
#define N0 4608
#define N1 2560
#define N2 768
#define N3 256
#define NTOT 8192

// Rolling GMS core, FULLY UNROLLED (compile-time TRIP, tail masked).
// R4 post-mortem: VGPR_Count=32 proved the loop back-edge collapsed the
// prefetch pipeline (allocator folds each load immediately -> one full HBM
// latency per row). Full unroll removes all back-edges: rotations become
// SSA renames, loads can stay in flight across bodies with counted waitcnts.
template<int TRIP, class LoadFn, class PoolFn>
__device__ __forceinline__ float gms_core(int lane, int Hk, int R0, int iend, int c,
                                          int phalf, LoadFn loadrow2, PoolFn dopool)
{
    auto medrow = [&](float ga, float gb, float gc, float& m, float& rs) {
        float lo = fminf(fminf(ga, gb), gc);
        float me = med3f(ga, gb, gc);
        float hi = fmaxf(fmaxf(ga, gb), gc);
        float lmax = fmaxf(fmaxf(dppL(lo), lo), dppR(lo));
        float mid  = med3f(dppL(me), me, dppR(me));
        float hmin = fminf(fminf(dppL(hi), hi), dppR(hi));
        m  = med3f(lmax, mid, hmin);
        rs = m + dppL(m) + dppR(m);
    };

    float xa, ya, xb, yb, xc, yc, xd, yd, xe, ye;
    loadrow2(R0 - 1, xa, ya);
    loadrow2(R0,     xb, yb);
    loadrow2(R0 + 1, xc, yc);
    loadrow2(R0 + 2, xd, yd);
    loadrow2(R0 + 3, xe, ye);

    // depth-2 prefetch: n0 = row i+4 (consumed this body), n1 = row i+5
    float n0x, n0y, n1x, n1y;
    loadrow2(R0 + 4, n0x, n0y);
    loadrow2(R0 + 5, n1x, n1y);

    float mx0, mx1, mx2, rx0, rx1, rx2;
    float my0, my1, my2, ry0, ry1, ry2;
    medrow(xa, xb, xc, mx0, rx0); medrow(ya, yb, yc, my0, ry0);
    dopool(xb, xc, yb, yc, phalf);             // pool gray rows (R0, R0+1)
    medrow(xb, xc, xd, mx1, rx1); medrow(yb, yc, yd, my1, ry1);
    medrow(xc, xd, xe, mx2, rx2); medrow(yc, yd, ye, my2, ry2);

    float gx2 = xd, gx3 = xe, gy2 = yd, gy3 = ye;  // gray rows i+2, i+3
    const bool outLane = (lane >= 2) && (lane <= 61) && (c <= Hk - 2);
    const float C9 = 9.0f * C_GMS;
    float acc = 0.0f;

    #pragma unroll
    for (int j = 0; j < TRIP; ++j) {
        const int i = R0 + j;
        // prefetch row i+6 (clamped+masked inside loadrow2; at the last
        // chunk the extra clamped rows are L2 hits, masked to zero)
        float pfx, pfy;
        loadrow2(i + 6, pfx, pfy);

        float csx = mx0 + mx1 + mx2;
        float csy = my0 + my1 + my2;
        float Gxx = dppR(csx) - dppL(csx);
        float Gxy = dppR(csy) - dppL(csy);
        float Gyx = rx0 - rx2;
        float Gyy = ry0 - ry2;
        // gI = sqrt(a)/3, gR = sqrt(b)/3  =>
        // 1 - gmap = (a + b - 2*sqrt(a*b)) / (a + b + 9c)
        float a = fmaf(Gxx, Gxx, Gyx * Gyx);
        float b = fmaf(Gxy, Gxy, Gyy * Gyy);
        float t = a + b;
        float s = __builtin_amdgcn_sqrtf(a * b);
        float den = t + C9;
        float diff = fmaf(-2.0f, s, t);
        float r = __builtin_amdgcn_rcpf(den);
        if (outLane && (i < iend)) acc = fmaf(diff, r, acc);   // tail mask

        if (((i + 3) & 1) == 1) dopool(gx2, gx3, gy2, gy3, (i + 2) >> 1);

        float mxn, rxn, myn, ryn;
        medrow(gx2, gx3, n0x, mxn, rxn);
        medrow(gy2, gy3, n0y, myn, ryn);
        mx0 = mx1; mx1 = mx2; mx2 = mxn; rx0 = rx1; rx1 = rx2; rx2 = rxn;
        my0 = my1; my1 = my2; my2 = myn; ry0 = ry1; ry1 = ry2; ry2 = ryn;
        gx2 = gx3; gx3 = n0x; gy2 = gy3; gy3 = n0y;
        n0x = n1x; n0y = n1y; n1x = pfx; n1y = pfy;
    }

    for (int off = 32; off; off >>= 1) acc += __shfl_down(acc, off, 64);
    return acc;
}

// Dispatch A: scale0 from RGB + fused 2x2 pool -> X1/Y1. RC=16 fixed trip.
__global__ __launch_bounds__(256) void msgms_scale0(
    const float* __restrict__ Ii, const float* __restrict__ Ir,
    float* __restrict__ X1, float* __restrict__ Y1, float* __restrict__ P)
{
    const int lane = threadIdx.x & 63;
    const int u = blockIdx.x * 4 + (threadIdx.x >> 6);
    const int s  = u % 9;               // strip fastest: halo sharing in L2
    const int t1 = u / 9;
    const int k  = t1 % 32;             // 32 chunks of 16 rows
    const int b  = t1 / 32;

    const int c  = 60 * s - 1 + lane;
    const int R0 = k * 16;
    const int iend = min(R0 + 16, 510);

    const float* PX = Ii + (size_t)b * 3 * 262144;
    const float* PY = Ir + (size_t)b * 3 * 262144;

    // branchless load: clamp col once, fold pad-zero + 1/3 into cw
    const int cc = min(max(c, 0), 511);
    const float cw = ((c >= 0) && (c < 512)) ? (1.0f / 3.0f) : 0.0f;

    auto loadrow2 = [&](int r, float& vx, float& vy) {
        int rc = min(max(r, 0), 511);          // uniform (SALU)
        float m = (r == rc) ? cw : 0.0f;       // row-valid fold
        int o = rc * 512 + cc;
        float x0 = PX[o], x1 = PX[o + 262144], x2 = PX[o + 524288];
        float y0 = PY[o], y1 = PY[o + 262144], y2 = PY[o + 524288];
        vx = (x0 + x1 + x2) * m;
        vy = (y0 + y1 + y2) * m;
    };

    const int phalf = R0 >> 1;
    const int pend  = min(phalf + 8, 256);   // 16 gray rows -> 8 pooled rows
    const bool poolLane = ((lane & 1) == 1) && (lane <= 59) && (c + 1 < 512);
    auto dopool = [&](float bx, float cx, float by, float cy, int p) {
        if (p < phalf || p >= pend) return;   // uniform
        float ux = bx + cx, uy = by + cy;
        float hx = ux + dppR(ux);
        float hy = uy + dppR(uy);
        if (poolLane) {
            size_t o = ((size_t)b * 256 + p) * 256 + (c >> 1);
            X1[o] = hx * 0.25f;
            Y1[o] = hy * 0.25f;
        }
    };

    float acc = gms_core<16>(lane, 512, R0, iend, c, phalf, loadrow2, dopool);
    if (lane == 0) P[u] = acc;
}

// Dispatch B: scales 1-3 from X1/Y1 with GxG on-the-fly pooling (G=1,2,4).
// Plain stores; dispatch boundary provides coherence. ZERO fences/atomics.
template<int G>
__device__ __forceinline__ void phaseR(
    int u, const float* __restrict__ X1, const float* __restrict__ Y1,
    int nstrips, int nchunks, float* __restrict__ P)
{
    constexpr int Hk = 256 / G;
    const int lane = threadIdx.x & 63;
    const int s  = u % nstrips;
    const int t1 = u / nstrips;
    const int k  = t1 % nchunks;
    const int b  = t1 / nchunks;

    const int c  = 60 * s - 1 + lane;
    const int R0 = k * 8;
    const int iend = min(R0 + 8, Hk - 2);

    const float* Xp = X1 + (size_t)b * 65536;
    const float* Yp = Y1 + (size_t)b * 65536;

    // branchless load: clamped col + mask folded into pool scale
    const int cc = min(max(c, 0), Hk - 1);
    const float cval = ((c >= 0) && (c < Hk)) ? 1.0f : 0.0f;

    auto loadrow2 = [&](int r, float& vx, float& vy) {
        int rc = min(max(r, 0), Hk - 1);       // uniform (SALU)
        float m = (r == rc) ? cval : 0.0f;
        if constexpr (G == 1) {
            int o = rc * 256 + cc;
            vx = Xp[o] * m; vy = Yp[o] * m;
        } else if constexpr (G == 2) {
            int o = (rc * 2) * 256 + cc * 2;
            float2 a0 = *(const float2*)(Xp + o);
            float2 a1 = *(const float2*)(Xp + o + 256);
            float2 b0 = *(const float2*)(Yp + o);
            float2 b1 = *(const float2*)(Yp + o + 256);
            float q = 0.25f * m;
            vx = ((a0.x + a0.y) + (a1.x + a1.y)) * q;
            vy = ((b0.x + b0.y) + (b1.x + b1.y)) * q;
        } else {
            int o = (rc * 4) * 256 + cc * 4;
            float sx = 0.0f, sy = 0.0f;
            #pragma unroll
            for (int fr = 0; fr < 4; ++fr) {
                float4 t = *(const float4*)(Xp + o + fr * 256);
                float4 q = *(const float4*)(Yp + o + fr * 256);
                sx += (t.x + t.y) + (t.z + t.w);
                sy += (q.x + q.y) + (q.z + q.w);
            }
            float q = 0.0625f * m;
            vx = sx * q; vy = sy * q;
        }
    };
    auto nopool = [&](float, float, float, float, int) {};

    float acc = gms_core<8>(lane, Hk, R0, iend, c, 0, loadrow2, nopool);
    if (lane == 0) P[u] = acc;
}

__global__ __launch_bounds__(256) void msgms_rest(
    const float* __restrict__ X1, const float* __restrict__ Y1,
    float* __restrict__ P)
{
    const int u = blockIdx.x * 4 + (threadIdx.x >> 6);
    if      (u < N1)      phaseR<1>(u,           X1, Y1, 5, 32, P + N0);
    else if (u < N1 + N2) phaseR<2>(u - N1,      X1, Y1, 3, 16, P + N0 + N1);
    else                  phaseR<4>(u - N1 - N2, X1, Y1, 2,  8, P + N0 + N1 + N2);
}

// Dispatch C: one block, weighted sum of all partials. Plain loads.
__global__ __launch_bounds__(256) void msgms_final(
    const float* __restrict__ P, float* __restrict__ out)
{
    const int tid = threadIdx.x;
    const double w0 = 1.0 / (4.0 * 16.0 * 510.0 * 510.0);
    const double w1 = 1.0 / (4.0 * 16.0 * 254.0 * 254.0);
    const double w2 = 1.0 / (4.0 * 16.0 * 126.0 * 126.0);
    const double w3 = 1.0 / (4.0 * 16.0 * 62.0 * 62.0);
    double v = 0.0;
    for (int i = tid; i < NTOT; i += 256) {
        double w = (i < N0) ? w0 : (i < N0 + N1) ? w1 : (i < N0 + N1 + N2) ? w2 : w3;
        v += (double)P[i] * w;
    }
    for (int off = 32; off; off >>= 1) v += __shfl_down(v, off, 64);
    __shared__ double wsum[4];
    if ((tid & 63) == 0) wsum[tid >> 6] = v;
    __syncthreads();
    if (tid == 0) out[0] = (float)(wsum[0] + wsum[1] + wsum[2] + wsum[3]);
}

extern "C" void kernel_launch(void* const* d_in, const int* in_sizes, int n_in,
                              void* d_out, int out_size, void* d_ws, size_t ws_size,
                              hipStream_t stream) {
    const float* Ii = (const float*)d_in[0];
    const float* Ir = (const float*)d_in[1];
    float* out = (float*)d_out;

    char* ws = (char*)d_ws;
    float* P  = (float*)ws;                              // NTOT partials
    float* X1 = P + NTOT;                                // 16 x 256 x 256 gray
    float* Y1 = X1 + 16 * 256 * 256;

    msgms_scale0<<<N0 / 4, 256, 0, stream>>>(Ii, Ir, X1, Y1, P);
    msgms_rest<<<(N1 + N2 + N3) / 4, 256, 0, stream>>>(X1, Y1, P);
    msgms_final<<<1, 256, 0, stream>>>(P, out);
}